// Round 4
// baseline (235.428 us; speedup 1.0000x reference)
//
#include <hip/hip_runtime.h>

// Blur = separable 4-tap FIR, taps f = [1,3,3,1]/4 = [0.25,0.75,0.75,0.25],
// zero padding: 2 left/top, 1 right/bottom. out[i] = 0.25 x[i-2] + 0.75 x[i-1]
// + 0.75 x[i] + 0.25 x[i+1] per axis. Kernel is palindromic so flip is a no-op.

constexpr int W = 256;
constexpr int H = 256;
constexpr float F0 = 0.25f;
constexpr float F1 = 0.75f;

typedef float f32x4 __attribute__((ext_vector_type(4)));  // for nontemporal builtin

// Horizontally-filtered row, shuffle-free. Lane l owns cols [4l, 4l+3].
// Halo (x[4l-2], x[4l-1], x[4l+4]) comes from two tiny extra loads that hit
// the same cache lines the wave already fetches (L1-served; no extra HBM).
// Replaces 3 ds_permute + lgkmcnt(0) + exec-mask fixups per row.
__device__ __forceinline__ float4 hrow(const float* __restrict__ xp, int i,
                                       int lane, int col) {
    if ((unsigned)i >= (unsigned)H) return make_float4(0.f, 0.f, 0.f, 0.f);
    const float* r = xp + i * W;
    float4 v = *reinterpret_cast<const float4*>(r + col);
    // lane 0: clamp address into the row (avoid underrun), zero via cndmask.
    float2 L = *reinterpret_cast<const float2*>(r + (lane ? col - 2 : 0));
    float  R = r[lane < 63 ? col + 4 : W - 1];
    if (lane == 0)  { L.x = 0.f; L.y = 0.f; }   // left zero-pad (2)
    if (lane == 63) { R = 0.f; }                // right zero-pad (1)
    float4 h;
    h.x = F0 * L.x + F1 * L.y + F1 * v.x + F0 * v.y;
    h.y = F0 * L.y + F1 * v.x + F1 * v.y + F0 * v.z;
    h.z = F0 * v.x + F1 * v.y + F1 * v.z + F0 * v.w;
    h.w = F0 * v.y + F1 * v.z + F1 * v.w + F0 * R;
    return h;
}

// One wave per 64-row strip; 4 waves/block = one 256-row (n,c) plane per block.
// Rolling 4-row register window (named A/B/C/D, statically indexed).
__global__ __launch_bounds__(256) void blur_kernel(const float* __restrict__ x,
                                                   float* __restrict__ out) {
    const int plane = blockIdx.x;           // n*C + c
    const int wave  = threadIdx.x >> 6;     // 0..3 -> row strip
    const int lane  = threadIdx.x & 63;
    const float* xp = x + (size_t)plane * (H * W);
    float*       op = out + (size_t)plane * (H * W);
    const int r0  = wave * 64;              // first output row of this strip
    const int col = lane * 4;

    // Window: out row io needs h(io-2), h(io-1), h(io), h(io+1).
    float4 A = hrow(xp, r0 - 2, lane, col);
    float4 B = hrow(xp, r0 - 1, lane, col);
    float4 C = hrow(xp, r0,     lane, col);

#pragma unroll 8
    for (int t = 0; t < 64; ++t) {
        const int io = r0 + t;
        float4 D = hrow(xp, io + 1, lane, col);
        f32x4 o;
        o.x = F0 * (A.x + D.x) + F1 * (B.x + C.x);
        o.y = F0 * (A.y + D.y) + F1 * (B.y + C.y);
        o.z = F0 * (A.z + D.z) + F1 * (B.z + C.z);
        o.w = F0 * (A.w + D.w) + F1 * (B.w + C.w);
        // Output lines are never re-read: non-temporal store keeps L2 for input.
        __builtin_nontemporal_store(o, reinterpret_cast<f32x4*>(op + io * W + col));
        A = B; B = C; C = D;
    }
}

extern "C" void kernel_launch(void* const* d_in, const int* in_sizes, int n_in,
                              void* d_out, int out_size, void* d_ws, size_t ws_size,
                              hipStream_t stream) {
    const float* x = (const float*)d_in[0];
    float* o = (float*)d_out;
    const int planes = in_sizes[0] / (H * W);  // N*C = 2048
    blur_kernel<<<planes, 256, 0, stream>>>(x, o);
}

// Round 5
// 227.369 us; speedup vs baseline: 1.0354x; 1.0354x over previous
//
#include <hip/hip_runtime.h>

// Blur = separable 4-tap FIR, taps f = [1,3,3,1]/4 = [0.25,0.75,0.75,0.25],
// zero padding: 2 left/top, 1 right/bottom. out[i] = 0.25 x[i-2] + 0.75 x[i-1]
// + 0.75 x[i] + 0.25 x[i+1] per axis. Kernel is palindromic so flip is a no-op.

constexpr int W = 256;
constexpr int H = 256;
constexpr float F0 = 0.25f;
constexpr float F1 = 0.75f;

typedef float f32x4 __attribute__((ext_vector_type(4)));  // for nontemporal builtin

// Horizontal 4-tap pass on one row. Lane l holds columns [4l, 4l+3] in v.
// Needs x[4l-2], x[4l-1] (prev lane's .z/.w) and x[4l+4] (next lane's .x).
__device__ __forceinline__ float4 hfilt(const float4 v, const int lane) {
    float xl2 = __shfl_up(v.z, 1);    // x[4l-2]
    float xl1 = __shfl_up(v.w, 1);    // x[4l-1]
    float xr  = __shfl_down(v.x, 1);  // x[4l+4]
    if (lane == 0)  { xl2 = 0.0f; xl1 = 0.0f; }  // left zero-pad (2)
    if (lane == 63) { xr = 0.0f; }               // right zero-pad (1)
    float4 h;
    h.x = F0 * xl2 + F1 * xl1 + F1 * v.x + F0 * v.y;
    h.y = F0 * xl1 + F1 * v.x + F1 * v.y + F0 * v.z;
    h.z = F0 * v.x + F1 * v.y + F1 * v.z + F0 * v.w;
    h.w = F0 * v.y + F1 * v.z + F1 * v.w + F0 * xr;
    return h;
}

// One wave per 64-row strip; 4 waves/block = one 256-row (n,c) plane per block.
// Rolling 4-row register window (named A/B/C/D — static indexing, no scratch).
// __launch_bounds__(256, 8): force VGPR<=64 so 8 blocks (32 waves) fit per CU —
// occupancy is the one untested variable for the 75%-of-copy-BW plateau.
__global__ __launch_bounds__(256, 8) void blur_kernel(const float* __restrict__ x,
                                                      float* __restrict__ out) {
    const int plane = blockIdx.x;           // n*C + c
    const int wave  = threadIdx.x >> 6;     // 0..3 -> row strip
    const int lane  = threadIdx.x & 63;
    const float* xp = x + (size_t)plane * (H * W);
    float*       op = out + (size_t)plane * (H * W);
    const int r0  = wave * 64;              // first output row of this strip
    const int col = lane * 4;

    auto loadrow = [&](int i) -> float4 {
        if ((unsigned)i >= (unsigned)H) return make_float4(0.f, 0.f, 0.f, 0.f);
        return *reinterpret_cast<const float4*>(xp + i * W + col);
    };

    // Window: out row io needs h(io-2), h(io-1), h(io), h(io+1).
    float4 A = hfilt(loadrow(r0 - 2), lane);
    float4 B = hfilt(loadrow(r0 - 1), lane);
    float4 C = hfilt(loadrow(r0), lane);

#pragma unroll 4
    for (int t = 0; t < 64; ++t) {
        const int io = r0 + t;
        float4 D = hfilt(loadrow(io + 1), lane);
        f32x4 o;
        o.x = F0 * (A.x + D.x) + F1 * (B.x + C.x);
        o.y = F0 * (A.y + D.y) + F1 * (B.y + C.y);
        o.z = F0 * (A.z + D.z) + F1 * (B.z + C.z);
        o.w = F0 * (A.w + D.w) + F1 * (B.w + C.w);
        // Output lines are never re-read: non-temporal store keeps L2 for input.
        __builtin_nontemporal_store(o, reinterpret_cast<f32x4*>(op + io * W + col));
        A = B; B = C; C = D;
    }
}

extern "C" void kernel_launch(void* const* d_in, const int* in_sizes, int n_in,
                              void* d_out, int out_size, void* d_ws, size_t ws_size,
                              hipStream_t stream) {
    const float* x = (const float*)d_in[0];
    float* o = (float*)d_out;
    const int planes = in_sizes[0] / (H * W);  // N*C = 2048
    blur_kernel<<<planes, 256, 0, stream>>>(x, o);
}

// Round 6
// 221.421 us; speedup vs baseline: 1.0633x; 1.0269x over previous
//
#include <hip/hip_runtime.h>

// Blur = separable 4-tap FIR, taps [0.25,0.75,0.75,0.25], zero-pad (2,1)/(2,1).
// Software-pipelined: two named 4-row buffers; per group the order is
// consume -> issue refill LOADS -> then STORES. vmcnt retires in issue order,
// so keeping the waited-on loads OLDER than in-flight stores means store
// retirement never gates load visibility (the R0..R5 structural stall theory).

constexpr int W = 256;
constexpr int H = 256;
constexpr float F0 = 0.25f;
constexpr float F1 = 0.75f;

typedef float f32x4 __attribute__((ext_vector_type(4)));

// Horizontal 4-tap pass. Lane l holds cols [4l,4l+3]; halo via 3 shuffles.
__device__ __forceinline__ float4 hfilt(const float4 v, const int lane) {
    float xl2 = __shfl_up(v.z, 1);
    float xl1 = __shfl_up(v.w, 1);
    float xr  = __shfl_down(v.x, 1);
    if (lane == 0)  { xl2 = 0.0f; xl1 = 0.0f; }
    if (lane == 63) { xr = 0.0f; }
    float4 h;
    h.x = F0 * xl2 + F1 * xl1 + F1 * v.x + F0 * v.y;
    h.y = F0 * xl1 + F1 * v.x + F1 * v.y + F0 * v.z;
    h.z = F0 * v.x + F1 * v.y + F1 * v.z + F0 * v.w;
    h.w = F0 * v.y + F1 * v.z + F1 * v.w + F0 * xr;
    return h;
}

// Vertical 4-tap: out = F0*(A+D) + F1*(B+C), componentwise.
__device__ __forceinline__ float4 vfilt(const float4 A, const float4 B,
                                        const float4 C, const float4 D) {
    float4 o;
    o.x = F0 * (A.x + D.x) + F1 * (B.x + C.x);
    o.y = F0 * (A.y + D.y) + F1 * (B.y + C.y);
    o.z = F0 * (A.z + D.z) + F1 * (B.z + C.z);
    o.w = F0 * (A.w + D.w) + F1 * (B.w + C.w);
    return o;
}

__global__ __launch_bounds__(256) void blur_kernel(const float* __restrict__ x,
                                                   float* __restrict__ out) {
    const int plane = blockIdx.x;
    const int wave  = threadIdx.x >> 6;
    const int lane  = threadIdx.x & 63;
    const float* xp = x + (size_t)plane * (H * W);
    float*       op = out + (size_t)plane * (H * W);
    const int r0  = wave * 64;
    const int col = lane * 4;

    auto loadrow = [&](int i) -> float4 {
        if ((unsigned)i >= (unsigned)H) return make_float4(0.f, 0.f, 0.f, 0.f);
        return *reinterpret_cast<const float4*>(xp + i * W + col);
    };
    auto storerow = [&](int i, const float4 o) {
        *reinterpret_cast<float4*>(op + i * W + col) = o;
    };

    // Rolling window of hfilt'd rows: out io needs h(io-2),h(io-1),h(io),h(io+1).
    float4 A = hfilt(loadrow(r0 - 2), lane);
    float4 B = hfilt(loadrow(r0 - 1), lane);
    float4 C = hfilt(loadrow(r0), lane);

    // Two 4-row raw-input buffers, 8 rows in flight (named: static indexing).
    float4 a0 = loadrow(r0 + 1), a1 = loadrow(r0 + 2),
           a2 = loadrow(r0 + 3), a3 = loadrow(r0 + 4);
    float4 b0 = loadrow(r0 + 5), b1 = loadrow(r0 + 6),
           b2 = loadrow(r0 + 7), b3 = loadrow(r0 + 8);

#pragma unroll
    for (int g = 0; g < 8; ++g) {
        const int base = r0 + 8 * g;   // outputs base..base+7 this group

        // ---- half 1: consume a (rows base+1..base+4), outputs base..base+3
        float4 D0 = hfilt(a0, lane), D1 = hfilt(a1, lane),
               D2 = hfilt(a2, lane), D3 = hfilt(a3, lane);
        float4 o0 = vfilt(A,  B,  C,  D0);
        float4 o1 = vfilt(B,  C,  D0, D1);
        float4 o2 = vfilt(C,  D0, D1, D2);
        float4 o3 = vfilt(D0, D1, D2, D3);
        A = D1; B = D2; C = D3;
        if (g < 7) {  // refill a with rows base+9..base+12 BEFORE the stores
            a0 = loadrow(base + 9);  a1 = loadrow(base + 10);
            a2 = loadrow(base + 11); a3 = loadrow(base + 12);
        }
        storerow(base,     o0); storerow(base + 1, o1);
        storerow(base + 2, o2); storerow(base + 3, o3);

        // ---- half 2: consume b (rows base+5..base+8), outputs base+4..base+7
        float4 E0 = hfilt(b0, lane), E1 = hfilt(b1, lane),
               E2 = hfilt(b2, lane), E3 = hfilt(b3, lane);
        float4 p0 = vfilt(A,  B,  C,  E0);
        float4 p1 = vfilt(B,  C,  E0, E1);
        float4 p2 = vfilt(C,  E0, E1, E2);
        float4 p3 = vfilt(E0, E1, E2, E3);
        A = E1; B = E2; C = E3;
        if (g < 7) {  // refill b with rows base+13..base+16 BEFORE the stores
            b0 = loadrow(base + 13); b1 = loadrow(base + 14);
            b2 = loadrow(base + 15); b3 = loadrow(base + 16);
        }
        storerow(base + 4, p0); storerow(base + 5, p1);
        storerow(base + 6, p2); storerow(base + 7, p3);
    }
}

extern "C" void kernel_launch(void* const* d_in, const int* in_sizes, int n_in,
                              void* d_out, int out_size, void* d_ws, size_t ws_size,
                              hipStream_t stream) {
    const float* x = (const float*)d_in[0];
    float* o = (float*)d_out;
    const int planes = in_sizes[0] / (H * W);  // N*C = 2048
    blur_kernel<<<planes, 256, 0, stream>>>(x, o);
}